// Round 4
// baseline (2353.744 us; speedup 1.0000x reference)
//
#include <hip/hip_runtime.h>
#include <hip/hip_bf16.h>
#include <cstdint>
#include <cstddef>

// DeepGPCM / DKVMN recurrence.
//  - erase/add GEMVs folded through Wv: We@ve = sum_k w_k*(We@Wv)[:,k,q-1] + (We@bv+be)
//    -> fused table EA[q][d][8] = {e0..e3, a0..a3}  (one 32B contiguous chunk per (q,d)).
//  - per-question tables SC (scores vs Mk), SQ (Ws_q*qe+bs), BQ (tanh betas), DQ (Wdisc_q*qe).
//  - main kernel: 1 block / batch element, Mv[50] in register PAIRS (v_pk_fma_f32).
//    Summary weights Ws(:,0:200) live in VGPRs (20 f32x2/thread, loaded once) -> phase 2
//    touches LDS only via broadcast reads of s_read. 2 barriers/step; EA + SC gathers
//    software-pipelined one step ahead; softmax on wave1 (phase0), finale on wave3
//    (phase1, deferred one step).

namespace {
constexpr int kB   = 1024;
constexpr int kS   = 500;
constexpr int kQ   = 2000;
constexpr int kKD  = 50;
constexpr int kMem = 50;
constexpr int kD   = 200;
constexpr int kFC  = 50;

// ws layout in floats
constexpr size_t OFF_EA   = 0;                            // 2000*200*8 = 3,200,000
constexpr size_t OFF_SC   = OFF_EA + (size_t)kQ * kD * 8;
constexpr size_t OFF_SQ   = OFF_SC + 100064;              // SC: 2001*50
constexpr size_t OFF_BQ   = OFF_SQ + 100064;              // SQ: 2001*50
constexpr size_t OFF_DQ   = OFF_BQ + 8032;                // BQ: 2001*4
constexpr size_t OFF_CE   = OFF_DQ + 2016;                // DQ: 2001
constexpr size_t OFF_CA   = OFF_CE + 224;
constexpr size_t OFF_WET  = OFF_CA + 224;
constexpr size_t OFF_WAT  = OFF_WET + 40000;
}  // namespace

typedef float f32x2 __attribute__((ext_vector_type(2)));

__device__ __forceinline__ f32x2 pk_fma(f32x2 a, f32x2 b, f32x2 c) {
  f32x2 d;
  asm("v_pk_fma_f32 %0, %1, %2, %3" : "=v"(d) : "v"(a), "v"(b), "v"(c));
  return d;
}

__device__ __forceinline__ float fast_tanh(float x) {
  const float ax = fabsf(x);
  const float t = __expf(-2.f * ax);
  const float r = (1.f - t) / (1.f + t);
  return copysignf(r, x);
}
__device__ __forceinline__ float fast_sigmoid(float x) {
  return 1.f / (1.f + __expf(-x));
}
__device__ __forceinline__ float fast_softplus(float x) {
  return fmaxf(x, 0.f) + log1pf(__expf(-fabsf(x)));
}

// ---------------- prep 1: transposes + bias folds ----------------
__global__ void prep1_misc(const float* __restrict__ We, const float* __restrict__ Wa,
                           const float* __restrict__ bv, const float* __restrict__ be,
                           const float* __restrict__ ba, float* __restrict__ ws) {
  float* WeT = ws + OFF_WET;
  float* WaT = ws + OFF_WAT;
  float* ce  = ws + OFF_CE;
  float* ca  = ws + OFF_CA;
  const int gt = blockIdx.x * 256 + threadIdx.x;
  const int stride = gridDim.x * 256;
  for (int e = gt; e < kD * kD; e += stride) {
    const int i = e / kD;
    const int dd = e - i * kD;
    WeT[e] = We[dd * kD + i];
    WaT[e] = Wa[dd * kD + i];
  }
  for (int dd = gt; dd < kD; dd += stride) {
    float acc_e = be[dd], acc_a = ba[dd];
    for (int i = 0; i < kD; ++i) {
      acc_e = fmaf(We[dd * kD + i], bv[i], acc_e);
      acc_a = fmaf(Wa[dd * kD + i], bv[i], acc_a);
    }
    ce[dd] = acc_e;
    ca[dd] = acc_a;
  }
}

// ---------------- prep 2: fused EA table  (We@Wv | Wa@Wv) ----------------
__global__ void prep2_tables(const float* __restrict__ Wv, float* __restrict__ ws) {
  __shared__ float s_wv[4][kD];
  const int tid = threadIdx.x;
  const int qm1 = blockIdx.x;  // question-1 in [0,2000)
  for (int e = tid; e < 4 * kD; e += 256) {
    const int k = e / kD;
    const int i = e - k * kD;
    s_wv[k][i] = Wv[(size_t)i * (4 * kQ) + (size_t)k * kQ + qm1];
  }
  __syncthreads();
  const int d = tid;
  if (d < kD) {
    const float* WeT = ws + OFF_WET;
    const float* WaT = ws + OFF_WAT;
    float e0 = 0.f, e1 = 0.f, e2 = 0.f, e3 = 0.f;
    float a0 = 0.f, a1 = 0.f, a2 = 0.f, a3 = 0.f;
    for (int i = 0; i < kD; ++i) {
      const float we = WeT[i * kD + d];
      const float wa = WaT[i * kD + d];
      e0 = fmaf(we, s_wv[0][i], e0);
      e1 = fmaf(we, s_wv[1][i], e1);
      e2 = fmaf(we, s_wv[2][i], e2);
      e3 = fmaf(we, s_wv[3][i], e3);
      a0 = fmaf(wa, s_wv[0][i], a0);
      a1 = fmaf(wa, s_wv[1][i], a1);
      a2 = fmaf(wa, s_wv[2][i], a2);
      a3 = fmaf(wa, s_wv[3][i], a3);
    }
    float* dst = ws + OFF_EA + (size_t)qm1 * (kD * 8) + (size_t)d * 8;
    dst[0] = e0; dst[1] = e1; dst[2] = e2; dst[3] = e3;
    dst[4] = a0; dst[5] = a1; dst[6] = a2; dst[7] = a3;
  }
}

// ---------------- prep 3: per-question tables SC/SQ/BQ/DQ ----------------
__global__ void prep3_qtables(const float* __restrict__ q_embed_w, const float* __restrict__ Mk,
                              const float* __restrict__ Ws, const float* __restrict__ bs,
                              const float* __restrict__ Wbeta, const float* __restrict__ bbeta,
                              const float* __restrict__ Wdisc, float* __restrict__ ws) {
  __shared__ float s_qe[kKD];
  const int tid = threadIdx.x;
  const int q = blockIdx.x;  // 0..2000
  if (tid < kKD) s_qe[tid] = q_embed_w[q * kKD + tid];
  __syncthreads();
  if (tid < kMem) {
    float s = 0.f;
    for (int j = 0; j < kKD; ++j) s = fmaf(s_qe[j], Mk[tid * kKD + j], s);
    ws[OFF_SC + (size_t)q * kMem + tid] = s;
  }
  if (tid < kFC) {
    float s = bs[tid];
    for (int j = 0; j < kKD; ++j) s = fmaf(s_qe[j], Ws[tid * 250 + kD + j], s);
    ws[OFF_SQ + (size_t)q * kFC + tid] = s;
  }
  if (tid < 4) {
    float v = 0.f;
    if (tid < 3) {
      float s = bbeta[tid];
      for (int j = 0; j < kKD; ++j) s = fmaf(s_qe[j], Wbeta[tid * kKD + j], s);
      v = tanhf(s);
    }
    ws[OFF_BQ + (size_t)q * 4 + tid] = v;
  }
  if (tid == 0) {
    float s = 0.f;
    for (int j = 0; j < kKD; ++j) s = fmaf(s_qe[j], Wdisc[kFC + j], s);
    ws[OFF_DQ + q] = s;
  }
}

// ---------------- main recurrent kernel ----------------
__device__ __forceinline__ void do_finale(int l, float wth_f, float wds_f, float bth0,
                                          float bdisc0, const float (*s_part)[64],
                                          const float* s_sq_row, const float* s_bqdq_row,
                                          float* out_ptr) {
  float summ = 0.f;
  if (l < kFC) {
    const float sp = s_part[0][l] + s_part[1][l] + s_part[2][l] + s_part[3][l] +
                     s_part[4][l] + s_sq_row[l];
    summ = fast_tanh(sp);
  }
  float p1 = wth_f * summ;
  float p2 = wds_f * summ;
#pragma unroll
  for (int o = 1; o < 64; o <<= 1) {
    p1 += __shfl_xor(p1, o);
    p2 += __shfl_xor(p2, o);
  }
  if (l == 0) {
    const float theta = 3.f * (p1 + bth0);
    const float alpha = fast_softplus(p2 + s_bqdq_row[3] + bdisc0);
    const float c1 = alpha * (theta - s_bqdq_row[0]);
    const float c2 = c1 + alpha * (theta - s_bqdq_row[1]);
    const float c3 = c2 + alpha * (theta - s_bqdq_row[2]);
    const float mx = fmaxf(fmaxf(0.f, c1), fmaxf(c2, c3));
    const float x0 = __expf(0.f - mx);
    const float x1 = __expf(c1 - mx);
    const float x2 = __expf(c2 - mx);
    const float x3 = __expf(c3 - mx);
    const float inv = 1.f / (x0 + x1 + x2 + x3);
    float4 pr;
    pr.x = x0 * inv;
    pr.y = x1 * inv;
    pr.z = x2 * inv;
    pr.w = x3 * inv;
    *reinterpret_cast<float4*>(out_ptr) = pr;
  }
}

__launch_bounds__(256, 4)
__global__ void dkvmn_main(const int* __restrict__ q_data, const int* __restrict__ r_data,
                           const float* __restrict__ Mv0, const float* __restrict__ Ws,
                           const float* __restrict__ Wth, const float* __restrict__ bth,
                           const float* __restrict__ Wdisc, const float* __restrict__ bdisc,
                           const float* __restrict__ ws, float* __restrict__ out) {
  const int tid = threadIdx.x;
  const int b = blockIdx.x;
  const int lane = tid & 63;
  const int wid = tid >> 6;
  const float* EA = ws + OFF_EA;
  const float* SC = ws + OFF_SC;
  const float* SQ = ws + OFF_SQ;
  const float* BQ = ws + OFF_BQ;
  const float* DQ = ws + OFF_DQ;

  __shared__ __align__(16) float s_read[208];
  __shared__ __align__(16) float s_cw[64];
  __shared__ float s_part[5][64];
  __shared__ float s_sq[2][kFC];
  __shared__ float s_bqdq[2][4];
  __shared__ __align__(16) float s_wtab[4][4];
  __shared__ int s_q[kS];
  __shared__ int s_r[kS];

  if (tid < 16) {
    const int r = tid >> 2, k = tid & 3;
    s_wtab[r][k] = fmaxf(0.f, 1.f - fabsf((float)k - (float)r) / 3.f);
  }
  {
    const int* qrow = q_data + (size_t)b * kS;
    const int* rrow = r_data + (size_t)b * kS;
    for (int e = tid; e < kS; e += 256) {
      s_q[e] = qrow[e];
      s_r[e] = rrow[e];
    }
  }
  // summary weights resident in VGPRs: thread (c,f) owns Ws[f][c*40 .. c*40+39]
  const bool pact = (tid < 250);
  const int pc = tid / 50;
  const int pf = tid - pc * 50;
  f32x2 wreg[20];
  if (pact) {
    const float* wsrc = Ws + (size_t)pf * 250 + pc * 40;
#pragma unroll
    for (int j = 0; j < 20; ++j) {
      wreg[j][0] = wsrc[2 * j];
      wreg[j][1] = wsrc[2 * j + 1];
    }
  } else {
#pragma unroll
    for (int j = 0; j < 20; ++j) wreg[j] = f32x2{0.f, 0.f};
  }
  f32x2 mv[25];
  const int d = tid;
  const bool dact = (d < kD);
  float ce_d = 0.f, ca_d = 0.f;
  if (dact) {
#pragma unroll
    for (int m = 0; m < 25; ++m) {
      mv[m][0] = Mv0[(2 * m) * kD + d];
      mv[m][1] = Mv0[(2 * m + 1) * kD + d];
    }
    ce_d = ws[OFF_CE + d];
    ca_d = ws[OFF_CA + d];
  }
  float wth_f = 0.f, wds_f = 0.f;
  if (wid == 3 && lane < kFC) {
    wth_f = Wth[lane];
    wds_f = Wdisc[lane];
  }
  const float bth0 = bth[0];
  const float bdisc0 = bdisc[0];
  float* out_b = out + (size_t)b * kS * 4;
  __syncthreads();  // init fills visible

  // initial one-step-ahead prefetch for t=0
  const int q0 = s_q[0];
  float4 e_cur = make_float4(0.f, 0.f, 0.f, 0.f);
  float4 a_cur = e_cur;
  if (dact) {
    const float4* p0 = reinterpret_cast<const float4*>(EA + (size_t)(q0 - 1) * (kD * 8) + (size_t)d * 8);
    e_cur = p0[0];
    a_cur = p0[1];
  }
  float sc_cur = -1e30f;
  if (wid == 1 && lane < kMem) sc_cur = SC[(size_t)q0 * kMem + lane];

  for (int t = 0; t < kS; ++t) {
    const int pb = t & 1;
    const int q = s_q[t];
    const int qn = s_q[(t + 1 < kS) ? (t + 1) : t];
    // ---------------- phase 0 ----------------
    f32x2 en2 = {0.f, 0.f}, ad2 = {0.f, 0.f};
    float4 e_nxt = e_cur, a_nxt = a_cur;
    if (dact) {
      // issue next-step gather first (consumed next iteration)
      const float4* pn = reinterpret_cast<const float4*>(EA + (size_t)(qn - 1) * (kD * 8) + (size_t)d * 8);
      e_nxt = pn[0];
      a_nxt = pn[1];
      const float4 w4 = *reinterpret_cast<const float4*>(&s_wtab[s_r[t]][0]);
      float ep = ce_d, ap = ca_d;
      ep = fmaf(w4.x, e_cur.x, ep);
      ep = fmaf(w4.y, e_cur.y, ep);
      ep = fmaf(w4.z, e_cur.z, ep);
      ep = fmaf(w4.w, e_cur.w, ep);
      ap = fmaf(w4.x, a_cur.x, ap);
      ap = fmaf(w4.y, a_cur.y, ap);
      ap = fmaf(w4.z, a_cur.z, ap);
      ap = fmaf(w4.w, a_cur.w, ap);
      const float erase_d = fast_sigmoid(ep);
      const float add_d = fast_tanh(ap);
      en2[0] = -erase_d;
      en2[1] = -erase_d;
      ad2[0] = add_d;
      ad2[1] = add_d;
    }
    float sc_nxt = -1e30f;
    if (wid == 1) {  // softmax for step t (uses prefetched sc_cur)
      float mx = sc_cur;
#pragma unroll
      for (int o = 1; o < 64; o <<= 1) mx = fmaxf(mx, __shfl_xor(mx, o));
      const float ev = (lane < kMem) ? __expf(sc_cur - mx) : 0.f;
      float sm = ev;
#pragma unroll
      for (int o = 1; o < 64; o <<= 1) sm += __shfl_xor(sm, o);
      if (lane < kMem) s_cw[lane] = ev / sm;
      if (lane < kMem) sc_nxt = SC[(size_t)qn * kMem + lane];
    }
    if (wid == 2) {  // stage head inputs for step t's (deferred) finale
      if (lane < kFC) {
        s_sq[pb][lane] = SQ[(size_t)q * kFC + lane];
      } else if (lane < 53) {
        s_bqdq[pb][lane - 50] = BQ[(size_t)q * 4 + (lane - 50)];
      } else if (lane == 53) {
        s_bqdq[pb][3] = DQ[q];
      }
    }
    __syncthreads();  // B1: cw ready; previous s_part/s_sq safe to read
    // ---------------- phase 1 ----------------
    if (dact) {
      f32x2 r2a = {0.f, 0.f}, r2b = {0.f, 0.f};
      const float4* cw4 = reinterpret_cast<const float4*>(s_cw);
#pragma unroll
      for (int g = 0; g < 12; ++g) {
        const float4 c4 = cw4[g];
        const f32x2 clo = {c4.x, c4.y};
        const f32x2 chi = {c4.z, c4.w};
        r2a = pk_fma(clo, mv[2 * g], r2a);
        mv[2 * g] = pk_fma(clo, pk_fma(mv[2 * g], en2, ad2), mv[2 * g]);
        r2b = pk_fma(chi, mv[2 * g + 1], r2b);
        mv[2 * g + 1] = pk_fma(chi, pk_fma(mv[2 * g + 1], en2, ad2), mv[2 * g + 1]);
      }
      {
        const f32x2 clast = *reinterpret_cast<const f32x2*>(&s_cw[48]);
        r2a = pk_fma(clast, mv[24], r2a);
        mv[24] = pk_fma(clast, pk_fma(mv[24], en2, ad2), mv[24]);
      }
      s_read[d] = (r2a[0] + r2b[0]) + (r2a[1] + r2b[1]);
    }
    if (wid == 3 && t > 0) {  // finale for step t-1
      do_finale(lane, wth_f, wds_f, bth0, bdisc0, s_part, s_sq[pb ^ 1], s_bqdq[pb ^ 1],
                out_b + (size_t)(t - 1) * 4);
    }
    __syncthreads();  // B2: read ready; finale consumed s_part
    // ---------------- phase 2 ---------------- (weights in VGPRs; LDS reads are broadcast)
    if (pact) {
      const float4* rp = reinterpret_cast<const float4*>(s_read + pc * 40);
      f32x2 acc0 = {0.f, 0.f}, acc1 = {0.f, 0.f};
#pragma unroll
      for (int g = 0; g < 10; ++g) {
        const float4 rv = rp[g];
        const f32x2 rlo = {rv.x, rv.y};
        const f32x2 rhi = {rv.z, rv.w};
        acc0 = pk_fma(wreg[2 * g], rlo, acc0);
        acc1 = pk_fma(wreg[2 * g + 1], rhi, acc1);
      }
      s_part[pc][pf] = (acc0[0] + acc1[0]) + (acc0[1] + acc1[1]);
    }
    e_cur = e_nxt;
    a_cur = a_nxt;
    sc_cur = sc_nxt;
  }
  __syncthreads();  // s_part for t=S-1 ready
  if (wid == 3) {
    do_finale(lane, wth_f, wds_f, bth0, bdisc0, s_part, s_sq[(kS - 1) & 1],
              s_bqdq[(kS - 1) & 1], out_b + (size_t)(kS - 1) * 4);
  }
}

extern "C" void kernel_launch(void* const* d_in, const int* in_sizes, int n_in,
                              void* d_out, int out_size, void* d_ws, size_t ws_size,
                              hipStream_t stream) {
  (void)in_sizes; (void)n_in; (void)out_size; (void)ws_size;
  const int* q_data = (const int*)d_in[0];
  const int* r_data = (const int*)d_in[1];
  const float* q_embed_w = (const float*)d_in[2];
  const float* Mk = (const float*)d_in[3];
  const float* Mv0 = (const float*)d_in[4];
  const float* Wv = (const float*)d_in[5];
  const float* bv = (const float*)d_in[6];
  const float* We = (const float*)d_in[7];
  const float* be = (const float*)d_in[8];
  const float* Wa = (const float*)d_in[9];
  const float* ba = (const float*)d_in[10];
  const float* Ws = (const float*)d_in[11];
  const float* bs = (const float*)d_in[12];
  const float* Wth = (const float*)d_in[13];
  const float* bth = (const float*)d_in[14];
  const float* Wbeta = (const float*)d_in[15];
  const float* bbeta = (const float*)d_in[16];
  const float* Wdisc = (const float*)d_in[17];
  const float* bdisc = (const float*)d_in[18];
  float* out = (float*)d_out;
  float* ws = (float*)d_ws;

  hipLaunchKernelGGL(prep1_misc, dim3(64), dim3(256), 0, stream, We, Wa, bv, be, ba, ws);
  hipLaunchKernelGGL(prep2_tables, dim3(kQ), dim3(256), 0, stream, Wv, ws);
  hipLaunchKernelGGL(prep3_qtables, dim3(kQ + 1), dim3(64), 0, stream, q_embed_w, Mk, Ws, bs,
                     Wbeta, bbeta, Wdisc, ws);
  hipLaunchKernelGGL(dkvmn_main, dim3(kB), dim3(256), 0, stream, q_data, r_data, Mv0, Ws, Wth,
                     bth, Wdisc, bdisc, ws, out);
}

// Round 5
// 1389.131 us; speedup vs baseline: 1.6944x; 1.6944x over previous
//
#include <hip/hip_runtime.h>
#include <hip/hip_bf16.h>
#include <cstdint>
#include <cstddef>

// DeepGPCM / DKVMN recurrence.
//  - erase/add are pure functions of (q,r): precomputed table EAD[(q-1)*4+r][d] = {erase,add}
//    (sigmoid/tanh folded in at prep time). Main-loop phase0 = one 8B gather per thread.
//  - attention softmax is a pure function of q: precomputed CW[q][50].
//  - per-question tables SQ (Ws_q*qe+bs), BQ (tanh betas), DQ (Wdisc_q*qe).
//  - main kernel: 1 block / batch element, Mv[50] in register pairs (v_pk_fma_f32).
//    Phase2 summary GEMV via v_dot2_f32_f16 on LDS f16 weights.
//  - LDS-ONLY barriers (s_waitcnt lgkmcnt(0) + raw s_barrier): __syncthreads would drain
//    vmcnt(0) and expose the software-pipelined gathers every step. All cross-step global
//    prefetches (EAD/CW/SQ/BQ/DQ) stay in flight across barriers.

namespace {
constexpr int kB   = 1024;
constexpr int kS   = 500;
constexpr int kQ   = 2000;
constexpr int kKD  = 50;
constexpr int kMem = 50;
constexpr int kD   = 200;
constexpr int kFC  = 50;
constexpr int kWP  = 216;  // f16 pitch for s_wsh rows

// ws layout in floats
constexpr size_t OFF_EAD  = 0;                              // 2000*4*200*2 = 3,200,000
constexpr size_t OFF_CW   = OFF_EAD + (size_t)kQ * 4 * kD * 2;
constexpr size_t OFF_SQ   = OFF_CW + 100064;                // CW: 2001*50
constexpr size_t OFF_BQ   = OFF_SQ + 100064;                // SQ: 2001*50
constexpr size_t OFF_DQ   = OFF_BQ + 8032;                  // BQ: 2001*4
constexpr size_t OFF_CE   = OFF_DQ + 2016;                  // DQ: 2001
constexpr size_t OFF_CA   = OFF_CE + 224;
constexpr size_t OFF_WET  = OFF_CA + 224;
constexpr size_t OFF_WAT  = OFF_WET + 40000;
}  // namespace

typedef float f32x2 __attribute__((ext_vector_type(2)));
typedef _Float16 h2_t __attribute__((ext_vector_type(2)));

__device__ __forceinline__ f32x2 pk_fma(f32x2 a, f32x2 b, f32x2 c) {
  f32x2 d;
  asm("v_pk_fma_f32 %0, %1, %2, %3" : "=v"(d) : "v"(a), "v"(b), "v"(c));
  return d;
}

__device__ __forceinline__ void lds_barrier() {
  // barrier that waits only on LDS ops: keeps global prefetches in flight
  asm volatile("s_waitcnt lgkmcnt(0)" ::: "memory");
  __builtin_amdgcn_s_barrier();
  asm volatile("" ::: "memory");
}

__device__ __forceinline__ float fast_tanh(float x) {
  const float ax = fabsf(x);
  const float t = __expf(-2.f * ax);
  const float r = (1.f - t) / (1.f + t);
  return copysignf(r, x);
}
__device__ __forceinline__ float fast_softplus(float x) {
  return fmaxf(x, 0.f) + log1pf(__expf(-fabsf(x)));
}

// ---------------- prep 1: transposes + bias folds ----------------
__global__ void prep1_misc(const float* __restrict__ We, const float* __restrict__ Wa,
                           const float* __restrict__ bv, const float* __restrict__ be,
                           const float* __restrict__ ba, float* __restrict__ ws) {
  float* WeT = ws + OFF_WET;
  float* WaT = ws + OFF_WAT;
  float* ce  = ws + OFF_CE;
  float* ca  = ws + OFF_CA;
  const int gt = blockIdx.x * 256 + threadIdx.x;
  const int stride = gridDim.x * 256;
  for (int e = gt; e < kD * kD; e += stride) {
    const int i = e / kD;
    const int dd = e - i * kD;
    WeT[e] = We[dd * kD + i];
    WaT[e] = Wa[dd * kD + i];
  }
  for (int dd = gt; dd < kD; dd += stride) {
    float acc_e = be[dd], acc_a = ba[dd];
    for (int i = 0; i < kD; ++i) {
      acc_e = fmaf(We[dd * kD + i], bv[i], acc_e);
      acc_a = fmaf(Wa[dd * kD + i], bv[i], acc_a);
    }
    ce[dd] = acc_e;
    ca[dd] = acc_a;
  }
}

// ---------------- prep 2: EAD table = {sigmoid(We@ve+be), tanh(Wa@ve+ba)} per (q,r,d) ----
__global__ void prep2_ead(const float* __restrict__ Wv, float* __restrict__ ws) {
  __shared__ float s_wv[4][kD];
  const int tid = threadIdx.x;
  const int qm1 = blockIdx.x;  // question-1 in [0,2000)
  for (int e = tid; e < 4 * kD; e += 256) {
    const int k = e / kD;
    const int i = e - k * kD;
    s_wv[k][i] = Wv[(size_t)i * (4 * kQ) + (size_t)k * kQ + qm1];
  }
  __syncthreads();
  const int d = tid;
  if (d < kD) {
    const float* WeT = ws + OFF_WET;
    const float* WaT = ws + OFF_WAT;
    float e0 = 0.f, e1 = 0.f, e2 = 0.f, e3 = 0.f;
    float a0 = 0.f, a1 = 0.f, a2 = 0.f, a3 = 0.f;
    for (int i = 0; i < kD; ++i) {
      const float we = WeT[i * kD + d];
      const float wa = WaT[i * kD + d];
      e0 = fmaf(we, s_wv[0][i], e0);
      e1 = fmaf(we, s_wv[1][i], e1);
      e2 = fmaf(we, s_wv[2][i], e2);
      e3 = fmaf(we, s_wv[3][i], e3);
      a0 = fmaf(wa, s_wv[0][i], a0);
      a1 = fmaf(wa, s_wv[1][i], a1);
      a2 = fmaf(wa, s_wv[2][i], a2);
      a3 = fmaf(wa, s_wv[3][i], a3);
    }
    const float ced = ws[OFF_CE + d];
    const float cad = ws[OFF_CA + d];
    const float W[4][4] = {{1.f, 2.f / 3.f, 1.f / 3.f, 0.f},
                           {2.f / 3.f, 1.f, 2.f / 3.f, 1.f / 3.f},
                           {1.f / 3.f, 2.f / 3.f, 1.f, 2.f / 3.f},
                           {0.f, 1.f / 3.f, 2.f / 3.f, 1.f}};
#pragma unroll
    for (int r = 0; r < 4; ++r) {
      const float ep = ced + W[r][0] * e0 + W[r][1] * e1 + W[r][2] * e2 + W[r][3] * e3;
      const float ap = cad + W[r][0] * a0 + W[r][1] * a1 + W[r][2] * a2 + W[r][3] * a3;
      float2 v;
      v.x = 1.f / (1.f + expf(-ep));  // erase
      v.y = tanhf(ap);                // add
      *reinterpret_cast<float2*>(ws + OFF_EAD + ((size_t)(qm1 * 4 + r) * kD + d) * 2) = v;
    }
  }
}

// ---------------- prep 3: per-question tables CW/SQ/BQ/DQ ----------------
__global__ void prep3_qtables(const float* __restrict__ q_embed_w, const float* __restrict__ Mk,
                              const float* __restrict__ Ws, const float* __restrict__ bs,
                              const float* __restrict__ Wbeta, const float* __restrict__ bbeta,
                              const float* __restrict__ Wdisc, float* __restrict__ ws) {
  __shared__ float s_qe[kKD];
  const int tid = threadIdx.x;
  const int q = blockIdx.x;  // 0..2000
  if (tid < kKD) s_qe[tid] = q_embed_w[q * kKD + tid];
  __syncthreads();
  // attention weights: softmax over the 50 Mk scores (pure function of q)
  {
    float s = -1e30f;
    if (tid < kMem) {
      s = 0.f;
      for (int j = 0; j < kKD; ++j) s = fmaf(s_qe[j], Mk[tid * kKD + j], s);
    }
    float mx = s;
#pragma unroll
    for (int o = 1; o < 64; o <<= 1) mx = fmaxf(mx, __shfl_xor(mx, o));
    const float ev = (tid < kMem) ? expf(s - mx) : 0.f;
    float sm = ev;
#pragma unroll
    for (int o = 1; o < 64; o <<= 1) sm += __shfl_xor(sm, o);
    if (tid < kMem) ws[OFF_CW + (size_t)q * kMem + tid] = ev / sm;
  }
  if (tid < kFC) {
    float s = bs[tid];
    for (int j = 0; j < kKD; ++j) s = fmaf(s_qe[j], Ws[tid * 250 + kD + j], s);
    ws[OFF_SQ + (size_t)q * kFC + tid] = s;
  }
  if (tid < 4) {
    float v = 0.f;
    if (tid < 3) {
      float s = bbeta[tid];
      for (int j = 0; j < kKD; ++j) s = fmaf(s_qe[j], Wbeta[tid * kKD + j], s);
      v = tanhf(s);
    }
    ws[OFF_BQ + (size_t)q * 4 + tid] = v;
  }
  if (tid == 0) {
    float s = 0.f;
    for (int j = 0; j < kKD; ++j) s = fmaf(s_qe[j], Wdisc[kFC + j], s);
    ws[OFF_DQ + q] = s;
  }
}

// ---------------- main recurrent kernel ----------------
__device__ __forceinline__ void do_finale(int l, float wth_f, float wds_f, float bth0,
                                          float bdisc0, const float (*s_part)[64],
                                          const float* s_sq_row, const float* s_bqdq_row,
                                          float* out_ptr) {
  float summ = 0.f;
  if (l < kFC) {
    const float sp = s_part[0][l] + s_part[1][l] + s_part[2][l] + s_part[3][l] +
                     s_part[4][l] + s_sq_row[l];
    summ = fast_tanh(sp);
  }
  float p1 = wth_f * summ;
  float p2 = wds_f * summ;
#pragma unroll
  for (int o = 1; o < 64; o <<= 1) {
    p1 += __shfl_xor(p1, o);
    p2 += __shfl_xor(p2, o);
  }
  if (l == 0) {
    const float theta = 3.f * (p1 + bth0);
    const float alpha = fast_softplus(p2 + s_bqdq_row[3] + bdisc0);
    const float c1 = alpha * (theta - s_bqdq_row[0]);
    const float c2 = c1 + alpha * (theta - s_bqdq_row[1]);
    const float c3 = c2 + alpha * (theta - s_bqdq_row[2]);
    const float mx = fmaxf(fmaxf(0.f, c1), fmaxf(c2, c3));
    const float x0 = __expf(0.f - mx);
    const float x1 = __expf(c1 - mx);
    const float x2 = __expf(c2 - mx);
    const float x3 = __expf(c3 - mx);
    const float inv = 1.f / (x0 + x1 + x2 + x3);
    float4 pr;
    pr.x = x0 * inv;
    pr.y = x1 * inv;
    pr.z = x2 * inv;
    pr.w = x3 * inv;
    *reinterpret_cast<float4*>(out_ptr) = pr;
  }
}

__launch_bounds__(256, 4)
__global__ void dkvmn_main(const int* __restrict__ q_data, const int* __restrict__ r_data,
                           const float* __restrict__ Mv0, const float* __restrict__ Ws,
                           const float* __restrict__ Wth, const float* __restrict__ bth,
                           const float* __restrict__ Wdisc, const float* __restrict__ bdisc,
                           const float* __restrict__ ws, float* __restrict__ out) {
  const int tid = threadIdx.x;
  const int b = blockIdx.x;
  const int lane = tid & 63;
  const int wid = tid >> 6;
  const float* EAD = ws + OFF_EAD;
  const float* CW = ws + OFF_CW;
  const float* SQ = ws + OFF_SQ;
  const float* BQ = ws + OFF_BQ;
  const float* DQ = ws + OFF_DQ;

  __shared__ __align__(16) _Float16 s_wsh[kFC * kWP];  // f16 Ws(:,0:200) [f][d], pitch 216
  __shared__ __align__(16) _Float16 s_readh[208];      // f16 read vector
  __shared__ __align__(16) float s_cw[64];
  __shared__ float s_part[5][64];
  __shared__ float s_sq[2][kFC];
  __shared__ float s_bqdq[2][4];
  __shared__ int s_q[kS];
  __shared__ int s_qr[kS];

  for (int e = tid; e < kFC * kD; e += 256) {
    const int f = e / kD;
    const int dd = e - f * kD;
    s_wsh[f * kWP + dd] = (_Float16)Ws[f * 250 + dd];
  }
  {
    const int* qrow = q_data + (size_t)b * kS;
    const int* rrow = r_data + (size_t)b * kS;
    for (int e = tid; e < kS; e += 256) {
      const int qv = qrow[e];
      s_q[e] = qv;
      s_qr[e] = (qv - 1) * 4 + rrow[e];
    }
  }
  f32x2 mv[25];
  const int d = tid;
  const bool dact = (d < kD);
  if (dact) {
#pragma unroll
    for (int m = 0; m < 25; ++m) {
      mv[m][0] = Mv0[(2 * m) * kD + d];
      mv[m][1] = Mv0[(2 * m + 1) * kD + d];
    }
  }
  float wth_f = 0.f, wds_f = 0.f;
  if (wid == 3 && lane < kFC) {
    wth_f = Wth[lane];
    wds_f = Wdisc[lane];
  }
  const float bth0 = bth[0];
  const float bdisc0 = bdisc[0];
  float* out_b = out + (size_t)b * kS * 4;
  __syncthreads();  // init fills visible (full barrier once is fine)

  // one-step-ahead prefetch for t=0
  const int q0 = s_q[0];
  const int qr0 = s_qr[0];
  float2 ea_cur = make_float2(0.f, 0.f);
  if (dact) ea_cur = *reinterpret_cast<const float2*>(EAD + ((size_t)qr0 * kD + d) * 2);
  float cw_cur = 0.f;
  if (wid == 1 && lane < kMem) cw_cur = CW[(size_t)q0 * kMem + lane];
  float v2_cur = 0.f;
  if (wid == 2) {
    if (lane < kFC) v2_cur = SQ[(size_t)q0 * kFC + lane];
    else if (lane < 53) v2_cur = BQ[(size_t)q0 * 4 + (lane - 50)];
    else if (lane == 53) v2_cur = DQ[q0];
  }

  for (int t = 0; t < kS; ++t) {
    const int pb = t & 1;
    const int tn = (t + 1 < kS) ? (t + 1) : t;
    const int qn = s_q[tn];
    const int qrn = s_qr[tn];
    // ---------------- phase 0 ----------------
    f32x2 en2 = {0.f, 0.f}, ad2 = {0.f, 0.f};
    float2 ea_nxt = ea_cur;
    if (dact) {
      ea_nxt = *reinterpret_cast<const float2*>(EAD + ((size_t)qrn * kD + d) * 2);  // prefetch
      en2[0] = -ea_cur.x;
      en2[1] = -ea_cur.x;
      ad2[0] = ea_cur.y;
      ad2[1] = ea_cur.y;
    }
    if (wid == 1) {  // stage attention weights for step t; prefetch t+1
      if (lane < kMem) {
        s_cw[lane] = cw_cur;
        cw_cur = CW[(size_t)qn * kMem + lane];
      }
    }
    if (wid == 2) {  // stage head inputs for step t's (deferred) finale; prefetch t+1
      if (lane < kFC) {
        s_sq[pb][lane] = v2_cur;
        v2_cur = SQ[(size_t)qn * kFC + lane];
      } else if (lane < 53) {
        s_bqdq[pb][lane - 50] = v2_cur;
        v2_cur = BQ[(size_t)qn * 4 + (lane - 50)];
      } else if (lane == 53) {
        s_bqdq[pb][3] = v2_cur;
        v2_cur = DQ[qn];
      }
    }
    lds_barrier();  // B1: cw/sq staged; previous s_part consumed-safe
    // ---------------- phase 1 ----------------
    if (dact) {
      f32x2 r2a = {0.f, 0.f}, r2b = {0.f, 0.f};
      const float4* cw4 = reinterpret_cast<const float4*>(s_cw);
#pragma unroll
      for (int g = 0; g < 12; ++g) {
        const float4 c4 = cw4[g];
        const f32x2 clo = {c4.x, c4.y};
        const f32x2 chi = {c4.z, c4.w};
        r2a = pk_fma(clo, mv[2 * g], r2a);
        mv[2 * g] = pk_fma(clo, pk_fma(mv[2 * g], en2, ad2), mv[2 * g]);
        r2b = pk_fma(chi, mv[2 * g + 1], r2b);
        mv[2 * g + 1] = pk_fma(chi, pk_fma(mv[2 * g + 1], en2, ad2), mv[2 * g + 1]);
      }
      {
        const f32x2 clast = *reinterpret_cast<const f32x2*>(&s_cw[48]);
        r2a = pk_fma(clast, mv[24], r2a);
        mv[24] = pk_fma(clast, pk_fma(mv[24], en2, ad2), mv[24]);
      }
      s_readh[d] = (_Float16)((r2a[0] + r2b[0]) + (r2a[1] + r2b[1]));
    }
    if (wid == 3 && t > 0) {  // finale for step t-1
      do_finale(lane, wth_f, wds_f, bth0, bdisc0, s_part, s_sq[pb ^ 1], s_bqdq[pb ^ 1],
                out_b + (size_t)(t - 1) * 4);
    }
    lds_barrier();  // B2: read ready; finale consumed s_part
    // ---------------- phase 2 ----------------
    if (tid < 250) {
      const int pc = tid / 50;
      const int pf = tid - pc * 50;
      const float4* wp = reinterpret_cast<const float4*>(s_wsh + pf * kWP + pc * 40);
      const float4* rp = reinterpret_cast<const float4*>(s_readh + pc * 40);
      float acc0 = 0.f, acc1 = 0.f;
#pragma unroll
      for (int g = 0; g < 5; ++g) {
        const float4 wv = wp[g];
        const float4 rv = rp[g];
        acc0 = __builtin_amdgcn_fdot2(__builtin_bit_cast(h2_t, wv.x),
                                      __builtin_bit_cast(h2_t, rv.x), acc0, false);
        acc1 = __builtin_amdgcn_fdot2(__builtin_bit_cast(h2_t, wv.y),
                                      __builtin_bit_cast(h2_t, rv.y), acc1, false);
        acc0 = __builtin_amdgcn_fdot2(__builtin_bit_cast(h2_t, wv.z),
                                      __builtin_bit_cast(h2_t, rv.z), acc0, false);
        acc1 = __builtin_amdgcn_fdot2(__builtin_bit_cast(h2_t, wv.w),
                                      __builtin_bit_cast(h2_t, rv.w), acc1, false);
      }
      s_part[pc][pf] = acc0 + acc1;
    }
    ea_cur = ea_nxt;
  }
  __syncthreads();  // s_part for t=S-1 ready
  if (wid == 3) {
    do_finale(lane, wth_f, wds_f, bth0, bdisc0, s_part, s_sq[(kS - 1) & 1],
              s_bqdq[(kS - 1) & 1], out_b + (size_t)(kS - 1) * 4);
  }
}

extern "C" void kernel_launch(void* const* d_in, const int* in_sizes, int n_in,
                              void* d_out, int out_size, void* d_ws, size_t ws_size,
                              hipStream_t stream) {
  (void)in_sizes; (void)n_in; (void)out_size; (void)ws_size;
  const int* q_data = (const int*)d_in[0];
  const int* r_data = (const int*)d_in[1];
  const float* q_embed_w = (const float*)d_in[2];
  const float* Mk = (const float*)d_in[3];
  const float* Mv0 = (const float*)d_in[4];
  const float* Wv = (const float*)d_in[5];
  const float* bv = (const float*)d_in[6];
  const float* We = (const float*)d_in[7];
  const float* be = (const float*)d_in[8];
  const float* Wa = (const float*)d_in[9];
  const float* ba = (const float*)d_in[10];
  const float* Ws = (const float*)d_in[11];
  const float* bs = (const float*)d_in[12];
  const float* Wth = (const float*)d_in[13];
  const float* bth = (const float*)d_in[14];
  const float* Wbeta = (const float*)d_in[15];
  const float* bbeta = (const float*)d_in[16];
  const float* Wdisc = (const float*)d_in[17];
  const float* bdisc = (const float*)d_in[18];
  float* out = (float*)d_out;
  float* ws = (float*)d_ws;

  hipLaunchKernelGGL(prep1_misc, dim3(64), dim3(256), 0, stream, We, Wa, bv, be, ba, ws);
  hipLaunchKernelGGL(prep2_ead, dim3(kQ), dim3(256), 0, stream, Wv, ws);
  hipLaunchKernelGGL(prep3_qtables, dim3(kQ + 1), dim3(64), 0, stream, q_embed_w, Mk, Ws, bs,
                     Wbeta, bbeta, Wdisc, ws);
  hipLaunchKernelGGL(dkvmn_main, dim3(kB), dim3(256), 0, stream, q_data, r_data, Mv0, Ws, Wth,
                     bth, Wdisc, bdisc, ws, out);
}

// Round 6
// 1246.140 us; speedup vs baseline: 1.8888x; 1.1147x over previous
//
#include <hip/hip_runtime.h>
#include <hip/hip_bf16.h>
#include <cstdint>
#include <cstddef>

// DeepGPCM / DKVMN recurrence.
//  - erase/add are pure functions of (q,r): precomputed table EAD[(q-1)*4+r][d] = {erase,add}.
//  - attention softmax pure function of q: precomputed CW[q][50].
//  - per-question tables SQ (Ws_q*qe+bs), BQ (tanh betas), DQ (Wdisc_q*qe).
//  - main kernel: 1 block / batch element, Mv[50] in register pairs (v_pk_fma_f32).
//    SINGLE lds-only barrier per step: all LDS buffers are cross-step double-buffered
//    (s_cw/s_readh/s_part x2, s_sq/s_bqdq x3). Phase2 consumes read[t-1]; finale consumes
//    step t-2. Epilogue drains the 2-deep pipeline.
//  - LDS-only barriers (s_waitcnt lgkmcnt(0) + raw s_barrier) keep the software-pipelined
//    global gathers (EAD/CW/SQ/BQ/DQ) in flight across barriers.

namespace {
constexpr int kB   = 1024;
constexpr int kS   = 500;
constexpr int kQ   = 2000;
constexpr int kKD  = 50;
constexpr int kMem = 50;
constexpr int kD   = 200;
constexpr int kFC  = 50;
constexpr int kWP  = 216;  // f16 pitch for s_wsh rows

// ws layout in floats
constexpr size_t OFF_EAD  = 0;                              // 2000*4*200*2 = 3,200,000
constexpr size_t OFF_CW   = OFF_EAD + (size_t)kQ * 4 * kD * 2;
constexpr size_t OFF_SQ   = OFF_CW + 100064;                // CW: 2001*50
constexpr size_t OFF_BQ   = OFF_SQ + 100064;                // SQ: 2001*50
constexpr size_t OFF_DQ   = OFF_BQ + 8032;                  // BQ: 2001*4
constexpr size_t OFF_CE   = OFF_DQ + 2016;                  // DQ: 2001
constexpr size_t OFF_CA   = OFF_CE + 224;
constexpr size_t OFF_WET  = OFF_CA + 224;
constexpr size_t OFF_WAT  = OFF_WET + 40000;
}  // namespace

typedef float f32x2 __attribute__((ext_vector_type(2)));
typedef _Float16 h2_t __attribute__((ext_vector_type(2)));

__device__ __forceinline__ f32x2 pk_fma(f32x2 a, f32x2 b, f32x2 c) {
  f32x2 d;
  asm("v_pk_fma_f32 %0, %1, %2, %3" : "=v"(d) : "v"(a), "v"(b), "v"(c));
  return d;
}

__device__ __forceinline__ void lds_barrier() {
  // barrier that waits only on LDS ops: keeps global prefetches in flight
  asm volatile("s_waitcnt lgkmcnt(0)" ::: "memory");
  __builtin_amdgcn_s_barrier();
  asm volatile("" ::: "memory");
}

__device__ __forceinline__ float fast_tanh(float x) {
  const float ax = fabsf(x);
  const float t = __expf(-2.f * ax);
  const float r = (1.f - t) / (1.f + t);
  return copysignf(r, x);
}
__device__ __forceinline__ float fast_softplus(float x) {
  return fmaxf(x, 0.f) + log1pf(__expf(-fabsf(x)));
}

// ---------------- prep 1: transposes + bias folds ----------------
__global__ void prep1_misc(const float* __restrict__ We, const float* __restrict__ Wa,
                           const float* __restrict__ bv, const float* __restrict__ be,
                           const float* __restrict__ ba, float* __restrict__ ws) {
  float* WeT = ws + OFF_WET;
  float* WaT = ws + OFF_WAT;
  float* ce  = ws + OFF_CE;
  float* ca  = ws + OFF_CA;
  const int gt = blockIdx.x * 256 + threadIdx.x;
  const int stride = gridDim.x * 256;
  for (int e = gt; e < kD * kD; e += stride) {
    const int i = e / kD;
    const int dd = e - i * kD;
    WeT[e] = We[dd * kD + i];
    WaT[e] = Wa[dd * kD + i];
  }
  for (int dd = gt; dd < kD; dd += stride) {
    float acc_e = be[dd], acc_a = ba[dd];
    for (int i = 0; i < kD; ++i) {
      acc_e = fmaf(We[dd * kD + i], bv[i], acc_e);
      acc_a = fmaf(Wa[dd * kD + i], bv[i], acc_a);
    }
    ce[dd] = acc_e;
    ca[dd] = acc_a;
  }
}

// ---------------- prep 2: EAD table = {sigmoid(We@ve+be), tanh(Wa@ve+ba)} per (q,r,d) ----
__global__ void prep2_ead(const float* __restrict__ Wv, float* __restrict__ ws) {
  __shared__ float s_wv[4][kD];
  const int tid = threadIdx.x;
  const int qm1 = blockIdx.x;  // question-1 in [0,2000)
  for (int e = tid; e < 4 * kD; e += 256) {
    const int k = e / kD;
    const int i = e - k * kD;
    s_wv[k][i] = Wv[(size_t)i * (4 * kQ) + (size_t)k * kQ + qm1];
  }
  __syncthreads();
  const int d = tid;
  if (d < kD) {
    const float* WeT = ws + OFF_WET;
    const float* WaT = ws + OFF_WAT;
    float e0 = 0.f, e1 = 0.f, e2 = 0.f, e3 = 0.f;
    float a0 = 0.f, a1 = 0.f, a2 = 0.f, a3 = 0.f;
    for (int i = 0; i < kD; ++i) {
      const float we = WeT[i * kD + d];
      const float wa = WaT[i * kD + d];
      e0 = fmaf(we, s_wv[0][i], e0);
      e1 = fmaf(we, s_wv[1][i], e1);
      e2 = fmaf(we, s_wv[2][i], e2);
      e3 = fmaf(we, s_wv[3][i], e3);
      a0 = fmaf(wa, s_wv[0][i], a0);
      a1 = fmaf(wa, s_wv[1][i], a1);
      a2 = fmaf(wa, s_wv[2][i], a2);
      a3 = fmaf(wa, s_wv[3][i], a3);
    }
    const float ced = ws[OFF_CE + d];
    const float cad = ws[OFF_CA + d];
    const float W[4][4] = {{1.f, 2.f / 3.f, 1.f / 3.f, 0.f},
                           {2.f / 3.f, 1.f, 2.f / 3.f, 1.f / 3.f},
                           {1.f / 3.f, 2.f / 3.f, 1.f, 2.f / 3.f},
                           {0.f, 1.f / 3.f, 2.f / 3.f, 1.f}};
#pragma unroll
    for (int r = 0; r < 4; ++r) {
      const float ep = ced + W[r][0] * e0 + W[r][1] * e1 + W[r][2] * e2 + W[r][3] * e3;
      const float ap = cad + W[r][0] * a0 + W[r][1] * a1 + W[r][2] * a2 + W[r][3] * a3;
      float2 v;
      v.x = 1.f / (1.f + expf(-ep));  // erase
      v.y = tanhf(ap);                // add
      *reinterpret_cast<float2*>(ws + OFF_EAD + ((size_t)(qm1 * 4 + r) * kD + d) * 2) = v;
    }
  }
}

// ---------------- prep 3: per-question tables CW/SQ/BQ/DQ ----------------
__global__ void prep3_qtables(const float* __restrict__ q_embed_w, const float* __restrict__ Mk,
                              const float* __restrict__ Ws, const float* __restrict__ bs,
                              const float* __restrict__ Wbeta, const float* __restrict__ bbeta,
                              const float* __restrict__ Wdisc, float* __restrict__ ws) {
  __shared__ float s_qe[kKD];
  const int tid = threadIdx.x;
  const int q = blockIdx.x;  // 0..2000
  if (tid < kKD) s_qe[tid] = q_embed_w[q * kKD + tid];
  __syncthreads();
  // attention weights: softmax over the 50 Mk scores (pure function of q)
  {
    float s = -1e30f;
    if (tid < kMem) {
      s = 0.f;
      for (int j = 0; j < kKD; ++j) s = fmaf(s_qe[j], Mk[tid * kKD + j], s);
    }
    float mx = s;
#pragma unroll
    for (int o = 1; o < 64; o <<= 1) mx = fmaxf(mx, __shfl_xor(mx, o));
    const float ev = (tid < kMem) ? expf(s - mx) : 0.f;
    float sm = ev;
#pragma unroll
    for (int o = 1; o < 64; o <<= 1) sm += __shfl_xor(sm, o);
    if (tid < kMem) ws[OFF_CW + (size_t)q * kMem + tid] = ev / sm;
  }
  if (tid < kFC) {
    float s = bs[tid];
    for (int j = 0; j < kKD; ++j) s = fmaf(s_qe[j], Ws[tid * 250 + kD + j], s);
    ws[OFF_SQ + (size_t)q * kFC + tid] = s;
  }
  if (tid < 4) {
    float v = 0.f;
    if (tid < 3) {
      float s = bbeta[tid];
      for (int j = 0; j < kKD; ++j) s = fmaf(s_qe[j], Wbeta[tid * kKD + j], s);
      v = tanhf(s);
    }
    ws[OFF_BQ + (size_t)q * 4 + tid] = v;
  }
  if (tid == 0) {
    float s = 0.f;
    for (int j = 0; j < kKD; ++j) s = fmaf(s_qe[j], Wdisc[kFC + j], s);
    ws[OFF_DQ + q] = s;
  }
}

// ---------------- main recurrent kernel ----------------
__device__ __forceinline__ void do_finale(int l, float wth_f, float wds_f, float bth0,
                                          float bdisc0, const float (*s_part)[64],
                                          const float* s_sq_row, const float* s_bqdq_row,
                                          float* out_ptr) {
  float summ = 0.f;
  if (l < kFC) {
    const float sp = s_part[0][l] + s_part[1][l] + s_part[2][l] + s_part[3][l] +
                     s_part[4][l] + s_sq_row[l];
    summ = fast_tanh(sp);
  }
  float p1 = wth_f * summ;
  float p2 = wds_f * summ;
#pragma unroll
  for (int o = 1; o < 64; o <<= 1) {
    p1 += __shfl_xor(p1, o);
    p2 += __shfl_xor(p2, o);
  }
  if (l == 0) {
    const float theta = 3.f * (p1 + bth0);
    const float alpha = fast_softplus(p2 + s_bqdq_row[3] + bdisc0);
    const float c1 = alpha * (theta - s_bqdq_row[0]);
    const float c2 = c1 + alpha * (theta - s_bqdq_row[1]);
    const float c3 = c2 + alpha * (theta - s_bqdq_row[2]);
    const float mx = fmaxf(fmaxf(0.f, c1), fmaxf(c2, c3));
    const float x0 = __expf(0.f - mx);
    const float x1 = __expf(c1 - mx);
    const float x2 = __expf(c2 - mx);
    const float x3 = __expf(c3 - mx);
    const float inv = 1.f / (x0 + x1 + x2 + x3);
    float4 pr;
    pr.x = x0 * inv;
    pr.y = x1 * inv;
    pr.z = x2 * inv;
    pr.w = x3 * inv;
    *reinterpret_cast<float4*>(out_ptr) = pr;
  }
}

__launch_bounds__(256, 4)
__global__ void dkvmn_main(const int* __restrict__ q_data, const int* __restrict__ r_data,
                           const float* __restrict__ Mv0, const float* __restrict__ Ws,
                           const float* __restrict__ Wth, const float* __restrict__ bth,
                           const float* __restrict__ Wdisc, const float* __restrict__ bdisc,
                           const float* __restrict__ ws, float* __restrict__ out) {
  const int tid = threadIdx.x;
  const int b = blockIdx.x;
  const int lane = tid & 63;
  const int wid = tid >> 6;
  const float* EAD = ws + OFF_EAD;
  const float* CW = ws + OFF_CW;
  const float* SQ = ws + OFF_SQ;
  const float* BQ = ws + OFF_BQ;
  const float* DQ = ws + OFF_DQ;

  __shared__ __align__(16) _Float16 s_wsh[kFC * kWP];  // f16 Ws(:,0:200) [f][d], pitch 216
  __shared__ __align__(16) _Float16 s_readh[2][208];   // f16 read vector, double-buffered
  __shared__ __align__(16) float s_cw[2][64];          // attention weights, double-buffered
  __shared__ float s_part[2][5][64];                   // summary partials, double-buffered
  __shared__ float s_sq[3][52];                        // head inputs, triple-buffered
  __shared__ float s_bqdq[3][4];
  __shared__ int s_q[kS];
  __shared__ int s_qr[kS];

  for (int e = tid; e < kFC * kD; e += 256) {
    const int f = e / kD;
    const int dd = e - f * kD;
    s_wsh[f * kWP + dd] = (_Float16)Ws[f * 250 + dd];
  }
  {
    const int* qrow = q_data + (size_t)b * kS;
    const int* rrow = r_data + (size_t)b * kS;
    for (int e = tid; e < kS; e += 256) {
      const int qv = qrow[e];
      s_q[e] = qv;
      s_qr[e] = (qv - 1) * 4 + rrow[e];
    }
  }
  f32x2 mv[25];
  const int d = tid;
  const bool dact = (d < kD);
  if (dact) {
#pragma unroll
    for (int m = 0; m < 25; ++m) {
      mv[m][0] = Mv0[(2 * m) * kD + d];
      mv[m][1] = Mv0[(2 * m + 1) * kD + d];
    }
  }
  float wth_f = 0.f, wds_f = 0.f;
  if (wid == 3 && lane < kFC) {
    wth_f = Wth[lane];
    wds_f = Wdisc[lane];
  }
  const float bth0 = bth[0];
  const float bdisc0 = bdisc[0];
  float* out_b = out + (size_t)b * kS * 4;
  __syncthreads();  // init fills visible

  // prologue: stage step-0 consumables + register prefetch for step 1
  const int q0 = s_q[0];
  const int q1 = s_q[1];
  float2 ea_cur = make_float2(0.f, 0.f);
  if (dact) ea_cur = *reinterpret_cast<const float2*>(EAD + ((size_t)s_qr[0] * kD + d) * 2);
  float cw_cur = 0.f;
  if (wid == 1 && lane < kMem) {
    s_cw[0][lane] = CW[(size_t)q0 * kMem + lane];
    cw_cur = CW[(size_t)q1 * kMem + lane];
  }
  float v2_cur = 0.f;
  if (wid == 2) {
    if (lane < kFC) v2_cur = SQ[(size_t)q0 * kFC + lane];
    else if (lane < 53) v2_cur = BQ[(size_t)q0 * 4 + (lane - 50)];
    else if (lane == 53) v2_cur = DQ[q0];
  }
  __syncthreads();  // s_cw[0] visible

  int i3 = 0;  // t % 3
  for (int t = 0; t < kS; ++t) {
    const int pb = t & 1;
    const int ip1 = (i3 + 1 < 3) ? i3 + 1 : 0;  // (t+1)%3 == (t-2)%3
    const int tn1 = (t + 1 < kS) ? t + 1 : kS - 1;
    const int tn2 = (t + 2 < kS) ? t + 2 : kS - 1;
    // ---- issue prefetches + stage next-step LDS buffers ----
    f32x2 en2 = {0.f, 0.f}, ad2 = {0.f, 0.f};
    float2 ea_nxt = ea_cur;
    if (dact) {
      ea_nxt = *reinterpret_cast<const float2*>(EAD + ((size_t)s_qr[tn1] * kD + d) * 2);
      en2[0] = -ea_cur.x;
      en2[1] = -ea_cur.x;
      ad2[0] = ea_cur.y;
      ad2[1] = ea_cur.y;
    }
    if (wid == 1 && lane < kMem) {  // cw for step t+1; prefetch t+2
      s_cw[pb ^ 1][lane] = cw_cur;
      cw_cur = CW[(size_t)s_q[tn2] * kMem + lane];
    }
    if (wid == 2) {  // head inputs for step t (consumed by finale at t+2); prefetch t+1
      const int qn = s_q[tn1];
      if (lane < kFC) {
        s_sq[i3][lane] = v2_cur;
        v2_cur = SQ[(size_t)qn * kFC + lane];
      } else if (lane < 53) {
        s_bqdq[i3][lane - 50] = v2_cur;
        v2_cur = BQ[(size_t)qn * 4 + (lane - 50)];
      } else if (lane == 53) {
        s_bqdq[i3][3] = v2_cur;
        v2_cur = DQ[qn];
      }
    }
    // ---- phase 1: Mv update + read (consumes s_cw[pb], staged at t-1) ----
    if (dact) {
      f32x2 r2a = {0.f, 0.f}, r2b = {0.f, 0.f};
      const float4* cw4 = reinterpret_cast<const float4*>(s_cw[pb]);
#pragma unroll
      for (int g = 0; g < 12; ++g) {
        const float4 c4 = cw4[g];
        const f32x2 clo = {c4.x, c4.y};
        const f32x2 chi = {c4.z, c4.w};
        r2a = pk_fma(clo, mv[2 * g], r2a);
        mv[2 * g] = pk_fma(clo, pk_fma(mv[2 * g], en2, ad2), mv[2 * g]);
        r2b = pk_fma(chi, mv[2 * g + 1], r2b);
        mv[2 * g + 1] = pk_fma(chi, pk_fma(mv[2 * g + 1], en2, ad2), mv[2 * g + 1]);
      }
      {
        const f32x2 clast = *reinterpret_cast<const f32x2*>(&s_cw[pb][48]);
        r2a = pk_fma(clast, mv[24], r2a);
        mv[24] = pk_fma(clast, pk_fma(mv[24], en2, ad2), mv[24]);
      }
      s_readh[pb][d] = (_Float16)((r2a[0] + r2b[0]) + (r2a[1] + r2b[1]));
    }
    // ---- finale for step t-2 (consumes s_part[pb^1] written at t-1, s_sq[(t-2)%3]) ----
    if (wid == 3 && t >= 2) {
      do_finale(lane, wth_f, wds_f, bth0, bdisc0, s_part[pb ^ 1], s_sq[ip1], s_bqdq[ip1],
                out_b + (size_t)(t - 2) * 4);
    }
    // ---- phase 2: summary partials from read[t-1] (s_readh[pb^1]) ----
    if (tid < 250) {
      const int pc = tid / 50;
      const int pf = tid - pc * 50;
      const float4* wp = reinterpret_cast<const float4*>(s_wsh + pf * kWP + pc * 40);
      const float4* rp = reinterpret_cast<const float4*>(&s_readh[pb ^ 1][pc * 40]);
      float acc0 = 0.f, acc1 = 0.f;
#pragma unroll
      for (int g = 0; g < 5; ++g) {
        const float4 wv = wp[g];
        const float4 rv = rp[g];
        acc0 = __builtin_amdgcn_fdot2(__builtin_bit_cast(h2_t, wv.x),
                                      __builtin_bit_cast(h2_t, rv.x), acc0, false);
        acc1 = __builtin_amdgcn_fdot2(__builtin_bit_cast(h2_t, wv.y),
                                      __builtin_bit_cast(h2_t, rv.y), acc1, false);
        acc0 = __builtin_amdgcn_fdot2(__builtin_bit_cast(h2_t, wv.z),
                                      __builtin_bit_cast(h2_t, rv.z), acc0, false);
        acc1 = __builtin_amdgcn_fdot2(__builtin_bit_cast(h2_t, wv.w),
                                      __builtin_bit_cast(h2_t, rv.w), acc1, false);
      }
      s_part[pb][pc][pf] = acc0 + acc1;
    }
    lds_barrier();  // single per-step barrier
    ea_cur = ea_nxt;
    i3 = ip1;
  }
  // ---- epilogue: drain 2-deep pipeline (steps kS-2, kS-1) ----
  {
    constexpr int pbE = kS & 1;           // 0 for kS=500
    constexpr int i3a = (kS - 2) % 3;     // s_sq index for step kS-2
    constexpr int i3b = (kS - 1) % 3;     // s_sq index for step kS-1
    if (tid < 250) {  // partials from read[kS-1] (in s_readh[(kS-1)&1])
      const int pc = tid / 50;
      const int pf = tid - pc * 50;
      const float4* wp = reinterpret_cast<const float4*>(s_wsh + pf * kWP + pc * 40);
      const float4* rp = reinterpret_cast<const float4*>(&s_readh[(kS - 1) & 1][pc * 40]);
      float acc0 = 0.f, acc1 = 0.f;
#pragma unroll
      for (int g = 0; g < 5; ++g) {
        const float4 wv = wp[g];
        const float4 rv = rp[g];
        acc0 = __builtin_amdgcn_fdot2(__builtin_bit_cast(h2_t, wv.x),
                                      __builtin_bit_cast(h2_t, rv.x), acc0, false);
        acc1 = __builtin_amdgcn_fdot2(__builtin_bit_cast(h2_t, wv.y),
                                      __builtin_bit_cast(h2_t, rv.y), acc1, false);
        acc0 = __builtin_amdgcn_fdot2(__builtin_bit_cast(h2_t, wv.z),
                                      __builtin_bit_cast(h2_t, rv.z), acc0, false);
        acc1 = __builtin_amdgcn_fdot2(__builtin_bit_cast(h2_t, wv.w),
                                      __builtin_bit_cast(h2_t, rv.w), acc1, false);
      }
      s_part[pbE][pc][pf] = acc0 + acc1;
    }
    if (wid == 3) {  // finale for step kS-2: partials written at t=kS-1
      do_finale(lane, wth_f, wds_f, bth0, bdisc0, s_part[pbE ^ 1], s_sq[i3a], s_bqdq[i3a],
                out_b + (size_t)(kS - 2) * 4);
    }
    lds_barrier();
    if (wid == 3) {  // finale for step kS-1
      do_finale(lane, wth_f, wds_f, bth0, bdisc0, s_part[pbE], s_sq[i3b], s_bqdq[i3b],
                out_b + (size_t)(kS - 1) * 4);
    }
  }
}

extern "C" void kernel_launch(void* const* d_in, const int* in_sizes, int n_in,
                              void* d_out, int out_size, void* d_ws, size_t ws_size,
                              hipStream_t stream) {
  (void)in_sizes; (void)n_in; (void)out_size; (void)ws_size;
  const int* q_data = (const int*)d_in[0];
  const int* r_data = (const int*)d_in[1];
  const float* q_embed_w = (const float*)d_in[2];
  const float* Mk = (const float*)d_in[3];
  const float* Mv0 = (const float*)d_in[4];
  const float* Wv = (const float*)d_in[5];
  const float* bv = (const float*)d_in[6];
  const float* We = (const float*)d_in[7];
  const float* be = (const float*)d_in[8];
  const float* Wa = (const float*)d_in[9];
  const float* ba = (const float*)d_in[10];
  const float* Ws = (const float*)d_in[11];
  const float* bs = (const float*)d_in[12];
  const float* Wth = (const float*)d_in[13];
  const float* bth = (const float*)d_in[14];
  const float* Wbeta = (const float*)d_in[15];
  const float* bbeta = (const float*)d_in[16];
  const float* Wdisc = (const float*)d_in[17];
  const float* bdisc = (const float*)d_in[18];
  float* out = (float*)d_out;
  float* ws = (float*)d_ws;

  hipLaunchKernelGGL(prep1_misc, dim3(64), dim3(256), 0, stream, We, Wa, bv, be, ba, ws);
  hipLaunchKernelGGL(prep2_ead, dim3(kQ), dim3(256), 0, stream, Wv, ws);
  hipLaunchKernelGGL(prep3_qtables, dim3(kQ + 1), dim3(64), 0, stream, q_embed_w, Mk, Ws, bs,
                     Wbeta, bbeta, Wdisc, ws);
  hipLaunchKernelGGL(dkvmn_main, dim3(kB), dim3(256), 0, stream, q_data, r_data, Mv0, Ws, Wth,
                     bth, Wdisc, bdisc, ws, out);
}